// Round 18
// baseline (60.119 us; speedup 1.0000x reference)
//
#include <hip/hip_runtime.h>
#include <stdint.h>

#define EPS_BN 1e-5f

#define C 256
#define H 28
#define W 28
#define R196 196
#define M_TOT 12544
#define K1 2304

typedef __attribute__((ext_vector_type(4))) int   i32x4;
typedef __attribute__((ext_vector_type(4))) float f32x4;
typedef unsigned short ushort_t;
typedef unsigned int uint_t;

__device__ __forceinline__ char sgn_i8(float v) {
    return v > 0.f ? (char)1 : (v < 0.f ? (char)-1 : (char)0);
}
__device__ __forceinline__ uint_t sgn_b(float v) {
    return (uint_t)(unsigned char)sgn_i8(v);
}

__device__ __forceinline__ void gload16(const void* g, void* l) {
    __builtin_amdgcn_global_load_lds(
        (const __attribute__((address_space(1))) void*)g,
        (__attribute__((address_space(3))) void*)l, 16, 0, 0);
}

// Channel order on the conv1 K axis is IDENTITY: a1p[px][ic], bw1 k = tap*256+ic.

// ---------------------------------------------------------------------------
// Kernel 1 (512 threads): blocks 0..767 weight prep; blocks 768..1279
// sign(x+bias)->a1p + 2x2 avgpool. Phase A is MLP-batched: each thread owns
// one (channel, row-pair) = 14 back-to-back independent float4 loads (224B
// contiguous), so HBM latency is covered by in-flight bytes, not wave count.
// ---------------------------------------------------------------------------
__global__ __launch_bounds__(512) void prep_sign(
    const float* __restrict__ w1,
    const float* __restrict__ bn1_g, const float* __restrict__ bn1_b,
    const float* __restrict__ bn1_m, const float* __restrict__ bn1_v,
    const float* __restrict__ w21,
    const float* __restrict__ bn21_g, const float* __restrict__ bn21_b,
    const float* __restrict__ bn21_m, const float* __restrict__ bn21_v,
    const float* __restrict__ w22,
    const float* __restrict__ bn22_g, const float* __restrict__ bn22_b,
    const float* __restrict__ bn22_m, const float* __restrict__ bn22_v,
    const float* __restrict__ x, const float* __restrict__ bias,
    char* __restrict__ bw1, char* __restrict__ bw2,
    float* __restrict__ alpha1, float* __restrict__ beta1,
    float* __restrict__ alpha2, float* __restrict__ beta2,
    char* __restrict__ a1p, float* __restrict__ pool)
{
    __shared__ uint_t lsign[64 * 99];         // [cc][row*7+q], 25.3KB
    float* red = (float*)lsign;               // 512-float reduction aliases it
    const int bid = blockIdx.x;
    const int t = threadIdx.x;

    if (bid < 768) {
        if (bid < 256) {
            const int oc = bid;
            const float* w = w1 + oc * K1;
            float wv[9];
            float s = 0.f;
            if (t < 256) {
#pragma unroll
                for (int k = 0; k < 9; ++k) wv[k] = w[t * 9 + k];
#pragma unroll
                for (int k = 0; k < 9; ++k) s += fabsf(wv[k]);
            }
            red[t] = s; __syncthreads();
            for (int o = 256; o > 0; o >>= 1) {
                if (t < o) red[t] += red[t + o];
                __syncthreads();
            }
            const float scale = red[0] * (1.f / (float)K1);
            if (t == 0) {
                const float inv = bn1_g[oc] * rsqrtf(bn1_v[oc] + EPS_BN);
                alpha1[oc] = scale * inv;
                beta1[oc]  = bn1_b[oc] - bn1_m[oc] * inv;
            }
            if (t < 256) {
#pragma unroll
                for (int tap = 0; tap < 9; ++tap)
                    bw1[oc * K1 + tap * 256 + t] = sgn_i8(wv[tap]);
            }
        } else {
            const bool br2 = (bid >= 512);
            const int oc = (bid - 256) & 255;
            const float* w = (br2 ? w22 : w21) + oc * 256;
            red[t] = (t < 256) ? fabsf(w[t]) : 0.f;
            __syncthreads();
            for (int o = 256; o > 0; o >>= 1) {
                if (t < o) red[t] += red[t + o];
                __syncthreads();
            }
            const float scale = red[0] * (1.f / 256.f);
            const int n = oc + (br2 ? 256 : 0);
            if (t == 0) {
                const float g = br2 ? bn22_g[oc] : bn21_g[oc];
                const float b = br2 ? bn22_b[oc] : bn21_b[oc];
                const float m = br2 ? bn22_m[oc] : bn21_m[oc];
                const float v = br2 ? bn22_v[oc] : bn21_v[oc];
                const float inv = g * rsqrtf(v + EPS_BN);
                alpha2[n] = scale * inv;
                beta2[n]  = b - m * inv;
            }
            if (t < 256) bw2[n * 256 + t] = sgn_i8(w[t]);
        }
        return;
    }

    // ---- sign + pool: block = (b, cq, rh), 512 threads ----
    const int sb = bid - 768;               // b*8 + cq*2 + rh
    const int rh = sb & 1;                  // row half: ih in [14rh, 14rh+14)
    const int cq = (sb >> 1) & 3;           // channels [64cq, 64cq+64)
    const int b = sb >> 3;
    const float* xb = x + ((size_t)(b * 256 + 64 * cq) * 784 + rh * 392);

    // Phase A: one (cc, row-pair) per thread; 14 independent float4 loads.
    if (t < 448) {                          // 64cc x 7ihp
        const int cc = t / 7, ihp = t - cc * 7;
        const int c = 64 * cq + cc;
        const float bc = bias[c];
        const float* src = xb + cc * 784 + (2 * ihp) * 28;
        float4 v[14];                       // rows 2ihp (v[0..6]), 2ihp+1 (v[7..13])
#pragma unroll
        for (int k = 0; k < 14; ++k) v[k] = *(const float4*)(src + 4 * k);

        uint_t* l0 = &lsign[cc * 99 + 14 * ihp];
#pragma unroll
        for (int k = 0; k < 14; ++k) {
            const float4 vv = v[k];
            l0[k] = sgn_b(vv.x + bc) | (sgn_b(vv.y + bc) << 8) |
                    (sgn_b(vv.z + bc) << 16) | (sgn_b(vv.w + bc) << 24);
        }
        float* pdst = pool + (size_t)(b * 256 + c) * 196 + (7 * rh + ihp) * 14;
#pragma unroll
        for (int q = 0; q < 7; ++q) {
            float2 pr;
            pr.x = 0.25f * (v[q].x + v[q].y + v[q + 7].x + v[q + 7].y);
            pr.y = 0.25f * (v[q].z + v[q].w + v[q + 7].z + v[q + 7].w);
            *(float2*)(pdst + 2 * q) = pr;
        }
    }
    __syncthreads();

    // Phase B: 4ch x 4iw byte transpose; 16 lanes -> 64B contiguous stores.
    {
        const int tw = t & 15;              // word index within c-quarter
        for (int ii = (t >> 4); ii < 392; ii += 32) {   // 14row x 7q x 4j
            const int row = ii / 28, qj = ii - row * 28;
            const int q = qj >> 2, j = qj & 3;
            uint_t d[4];
#pragma unroll
            for (int e = 0; e < 4; ++e)
                d[e] = lsign[(4 * tw + e) * 99 + row * 7 + q];
            const uint_t ov = ((d[0] >> (8 * j)) & 0xffu)
                            | (((d[1] >> (8 * j)) & 0xffu) << 8)
                            | (((d[2] >> (8 * j)) & 0xffu) << 16)
                            | (((d[3] >> (8 * j)) & 0xffu) << 24);
            const int ihp = 14 * rh + row + 1;
            const int iwp = 4 * q + j + 1;
            *(uint_t*)(a1p + (size_t)((b * 30 + ihp) * 30 + iwp) * 256
                       + 64 * cq + 4 * tw) = ov;
        }
        // halo: this block zeroes its 64B channel slice for its row range
        for (int px = (t >> 4); px < 60; px += 32) {
            int ihp, iwp;
            if (px < 15)      { ihp = 15 * rh + px;        iwp = 0;  }
            else if (px < 30) { ihp = 15 * rh + (px - 15); iwp = 29; }
            else              { ihp = 29 * rh;             iwp = px - 30; }
            *(uint_t*)(a1p + (size_t)((b * 30 + ihp) * 30 + iwp) * 256
                       + 64 * cq + 4 * tw) = 0u;
        }
    }
}

// ---------------------------------------------------------------------------
// Kernel 2: conv1 (3x3 s2) i8 GEMM (= R16/R17: prefetch + LDS-transposed epi).
// ---------------------------------------------------------------------------
__global__ __launch_bounds__(512) void conv1_i8(
    const char* __restrict__ a1p,       // [64][30][30][256] i8
    const char* __restrict__ bw1,       // [256][2304] i8 (k = tap*256+ic)
    const float* __restrict__ alpha1, const float* __restrict__ beta1,
    const float* __restrict__ p,
    const float* __restrict__ rsb,
    const float* __restrict__ prg, const float* __restrict__ prb,
    const float* __restrict__ prz,
    float* __restrict__ out2,
    char* __restrict__ a2)              // [m][256] i8
{
    __shared__ char lA[2][64 * 128];    // 16KB (reused: fp32 otile [n][m])
    __shared__ char lB[2][64 * 128];    // 16KB (reused: i8 atile [m][n])

    const int bid = blockIdx.x;
    const int wgid = (bid & 7) * 98 + (bid >> 3);   // 784 = 8*98
    const int mtile = wgid >> 2;
    const int ntile = wgid & 3;

    const int tid = threadIdx.x;
    const int wave = tid >> 6;
    const int lane = tid & 63;
    const int col = lane & 15;
    const int krow = lane >> 4;
    const int wr = wave >> 2;
    const int wc = wave & 3;
    const int l8 = lane >> 3;
    const int s8 = lane & 7;
    const int swz = ((s8 ^ l8) << 4);

    int pbA;
    {
        const int grow = wave * 8 + l8;
        const int m = mtile * 64 + grow;
        const int b = m / 196, r = m % 196;
        const int oh = r / 14, ow = r % 14;
        pbA = ((b * 30 + 2 * oh) * 30 + 2 * ow) * 256 + swz;
    }
    const int pbB = (ntile * 64 + wave * 8 + l8) * K1 + swz;

    int rswz[2];
#pragma unroll
    for (int ks = 0; ks < 2; ++ks)
        rswz[ks] = ((ks * 4 + krow) ^ (col & 7)) << 4;

    // epilogue-operand prefetch (latency hides under the K-loop)
    const int n0e = ntile * 64 + wc * 16 + krow * 4;
    float p_pre[2][4];
#pragma unroll
    for (int im = 0; im < 2; ++im) {
        const int m = mtile * 64 + wr * 32 + im * 16 + col;
        const int b = m / 196, r = m % 196;
#pragma unroll
        for (int j = 0; j < 4; ++j)
            p_pre[im][j] = p[(b * 256 + n0e + j) * 196 + r];
    }

    i32x4 acc[2] = {};

    auto stage = [&](int step, int buf) {
        const int tap = step >> 1;
        const int kc0 = (step & 1) << 7;
        const int kh = tap / 3, kw = tap - kh * 3;
        const int aoff = (kh * 30 + kw) * 256 + kc0;
        gload16(a1p + pbA + aoff, &lA[buf][0] + wave * 1024);
        gload16(bw1 + pbB + step * 128, &lB[buf][0] + wave * 1024);
    };

    stage(0, 0);

    int cur = 0;
    for (int step = 0; step < 18; ++step) {
        if (step + 1 < 18) {
            stage(step + 1, cur ^ 1);
            asm volatile("s_waitcnt vmcnt(2)" ::: "memory");
        } else {
            asm volatile("s_waitcnt vmcnt(0)" ::: "memory");
        }
        __builtin_amdgcn_s_barrier();
        __builtin_amdgcn_sched_barrier(0);

#pragma unroll
        for (int ks = 0; ks < 2; ++ks) {
            i32x4 bf[2], af;
#pragma unroll
            for (int im = 0; im < 2; ++im) {
                const int row = wr * 32 + im * 16 + col;
                bf[im] = *(const i32x4*)(&lA[cur][0] + row * 128 + rswz[ks]);
            }
            {
                const int row = wc * 16 + col;
                af = *(const i32x4*)(&lB[cur][0] + row * 128 + rswz[ks]);
            }
#pragma unroll
            for (int im = 0; im < 2; ++im)
                acc[im] = __builtin_amdgcn_mfma_i32_16x16x64_i8(
                    af, bf[im], acc[im], 0, 0, 0);
        }
        __builtin_amdgcn_sched_barrier(0);
        __builtin_amdgcn_s_barrier();
        cur ^= 1;
    }

    // -------- LDS-transposed epilogue --------
    float* otile = (float*)&lA[0][0];     // [nl][ml] 64x64 f32
    char*  atile = &lB[0][0];             // [ml][nl] 64x64 i8
    __syncthreads();
#pragma unroll
    for (int im = 0; im < 2; ++im) {
        const int ml = wr * 32 + im * 16 + col;
#pragma unroll
        for (int j = 0; j < 4; ++j) {
            const int nl = wc * 16 + krow * 4 + j;
            const int n = ntile * 64 + nl;
            float v = alpha1[n] * (float)acc[im][j] + beta1[n] + p_pre[im][j];
            const float t = v - prg[n];
            const float o = (t > 0.f ? t : prb[n] * t) + prz[n];
            otile[nl * 64 + ml] = o;
            atile[ml * 64 + nl] = sgn_i8(o + rsb[n]);
        }
    }
    __syncthreads();
    {
        const int m = mtile * 64 + lane;
        const int b = m / 196, r = m % 196;
#pragma unroll
        for (int nn = 0; nn < 8; ++nn) {
            const int nl = wave * 8 + nn;
            out2[(b * 256 + ntile * 64 + nl) * 196 + r] = otile[nl * 64 + lane];
        }
    }
    {
        const uint_t* at32 = (const uint_t*)atile;
#pragma unroll
        for (int h = 0; h < 2; ++h) {
            const int idx = h * 512 + tid;
            const int ml = idx >> 4, nq = idx & 15;
            *(uint_t*)(a2 + (size_t)(mtile * 64 + ml) * 256 + ntile * 64 + nq * 4)
                = at32[ml * 16 + nq];
        }
    }
}

// ---------------------------------------------------------------------------
// Kernel 3: both 1x1 convs, single-shot i8 GEMM (= R16/R17).
// ---------------------------------------------------------------------------
__global__ __launch_bounds__(512) void conv1x1_i8(
    const char* __restrict__ a2,
    const char* __restrict__ bw2,
    const float* __restrict__ alpha2, const float* __restrict__ beta2,
    const float* __restrict__ out2,
    const float* __restrict__ prg, const float* __restrict__ prb,
    const float* __restrict__ prz,
    float* __restrict__ out)
{
    __shared__ char lA[2][64 * 128];    // 16KB (reused: fp32 otile [n][m])
    __shared__ char lB[2][64 * 128];

    const int bid = blockIdx.x;
    const int wgid = (bid & 7) * 196 + (bid >> 3);  // 1568 = 8*196
    const int mtile = wgid >> 3;
    const int ntile = wgid & 7;

    const int tid = threadIdx.x;
    const int wave = tid >> 6;
    const int lane = tid & 63;
    const int col = lane & 15;
    const int krow = lane >> 4;
    const int wr = wave >> 2;
    const int wc = wave & 3;
    const int l8 = lane >> 3;
    const int s8 = lane & 7;
    const int swz = ((s8 ^ l8) << 4);

    const int pbA = (mtile * 64 + wave * 8 + l8) * 256 + swz;
    const int pbB = (ntile * 64 + wave * 8 + l8) * 256 + swz;

    const int n0e = ntile * 64 + wc * 16 + krow * 4;
    float o2_pre[2][4];
#pragma unroll
    for (int im = 0; im < 2; ++im) {
        const int m = mtile * 64 + wr * 32 + im * 16 + col;
        const int b = m / 196, r = m % 196;
#pragma unroll
        for (int j = 0; j < 4; ++j)
            o2_pre[im][j] = out2[(b * 256 + ((n0e + j) & 255)) * 196 + r];
    }

#pragma unroll
    for (int h = 0; h < 2; ++h) {
        gload16(a2 + pbA + h * 128, &lA[h][0] + wave * 1024);
        gload16(bw2 + pbB + h * 128, &lB[h][0] + wave * 1024);
    }
    asm volatile("s_waitcnt vmcnt(0)" ::: "memory");
    __builtin_amdgcn_s_barrier();
    __builtin_amdgcn_sched_barrier(0);

    i32x4 acc[2] = {};
#pragma unroll
    for (int ks = 0; ks < 4; ++ks) {
        const int h = ks >> 1, k2 = ks & 1;
        const int ro = ((k2 * 4 + krow) ^ (col & 7)) << 4;
        i32x4 bf[2], af;
#pragma unroll
        for (int im = 0; im < 2; ++im) {
            const int row = wr * 32 + im * 16 + col;
            bf[im] = *(const i32x4*)(&lA[h][0] + row * 128 + ro);
        }
        {
            const int row = wc * 16 + col;
            af = *(const i32x4*)(&lB[h][0] + row * 128 + ro);
        }
#pragma unroll
        for (int im = 0; im < 2; ++im)
            acc[im] = __builtin_amdgcn_mfma_i32_16x16x64_i8(
                af, bf[im], acc[im], 0, 0, 0);
    }

    // -------- LDS-transposed epilogue --------
    float* otile = (float*)&lA[0][0];     // [nl][ml] 64x64 f32
    __syncthreads();
#pragma unroll
    for (int im = 0; im < 2; ++im) {
        const int ml = wr * 32 + im * 16 + col;
#pragma unroll
        for (int j = 0; j < 4; ++j) {
            const int nl = wc * 16 + krow * 4 + j;
            const int n = ntile * 64 + nl;             // [0,512)
            const int oc = n & 255;
            float v = alpha2[n] * (float)acc[im][j] + beta2[n] + o2_pre[im][j];
            const float t = v - prg[oc];
            otile[nl * 64 + ml] = (t > 0.f ? t : prb[oc] * t) + prz[oc];
        }
    }
    __syncthreads();
    {
        const int m = mtile * 64 + lane;
        const int b = m / 196, r = m % 196;
#pragma unroll
        for (int nn = 0; nn < 8; ++nn) {
            const int nl = wave * 8 + nn;
            out[(size_t)(b * 512 + ntile * 64 + nl) * 196 + r]
                = otile[nl * 64 + lane];
        }
    }
}

// ---------------------------------------------------------------------------
extern "C" void kernel_launch(void* const* d_in, const int* in_sizes, int n_in,
                              void* d_out, int out_size, void* d_ws, size_t ws_size,
                              hipStream_t stream)
{
    (void)in_sizes; (void)n_in; (void)out_size; (void)ws_size;

    const float* x         = (const float*)d_in[0];
    const float* rsign_b   = (const float*)d_in[1];
    const float* w1        = (const float*)d_in[2];
    const float* bn1_g     = (const float*)d_in[3];
    const float* bn1_b     = (const float*)d_in[4];
    const float* bn1_m     = (const float*)d_in[5];
    const float* bn1_v     = (const float*)d_in[6];
    const float* w21       = (const float*)d_in[7];
    const float* bn21_g    = (const float*)d_in[8];
    const float* bn21_b    = (const float*)d_in[9];
    const float* bn21_m    = (const float*)d_in[10];
    const float* bn21_v    = (const float*)d_in[11];
    const float* w22       = (const float*)d_in[12];
    const float* bn22_g    = (const float*)d_in[13];
    const float* bn22_b    = (const float*)d_in[14];
    const float* bn22_m    = (const float*)d_in[15];
    const float* bn22_v    = (const float*)d_in[16];
    const float* pr_gamma  = (const float*)d_in[17];
    const float* pr_beta   = (const float*)d_in[18];
    const float* pr_zeta   = (const float*)d_in[19];

    char* ws = (char*)d_ws;
    size_t off = 0;
    char* a1p     = (char*)(ws + off);  off += (size_t)14745600;      // i8
    char* bw1     = (char*)(ws + off);  off += (size_t)589824;        // i8
    char* bw2     = (char*)(ws + off);  off += (size_t)131072;        // i8
    float* pool   = (float*)(ws + off); off += (size_t)3211264 * 4;   // fp32
    float* out2   = (float*)(ws + off); off += (size_t)3211264 * 4;   // fp32
    char* a2      = (char*)(ws + off);  off += (size_t)3211264;       // i8
    float* alpha1 = (float*)(ws + off); off += 1024;
    float* beta1  = (float*)(ws + off); off += 1024;
    float* alpha2 = (float*)(ws + off); off += 2048;
    float* beta2  = (float*)(ws + off); off += 2048;

    prep_sign<<<1280, 512, 0, stream>>>(
        w1, bn1_g, bn1_b, bn1_m, bn1_v,
        w21, bn21_g, bn21_b, bn21_m, bn21_v,
        w22, bn22_g, bn22_b, bn22_m, bn22_v,
        x, rsign_b,
        bw1, bw2, alpha1, beta1, alpha2, beta2, a1p, pool);

    conv1_i8<<<784, 512, 0, stream>>>(
        a1p, bw1, alpha1, beta1, pool, rsign_b,
        pr_gamma, pr_beta, pr_zeta, out2, a2);

    conv1x1_i8<<<1568, 512, 0, stream>>>(
        a2, bw2, alpha2, beta2, out2,
        pr_gamma, pr_beta, pr_zeta, (float*)d_out);
}

// Round 19
// 56.403 us; speedup vs baseline: 1.0659x; 1.0659x over previous
//
#include <hip/hip_runtime.h>
#include <stdint.h>

#define EPS_BN 1e-5f

#define C 256
#define H 28
#define W 28
#define R196 196
#define M_TOT 12544
#define K1 2304

typedef __attribute__((ext_vector_type(4))) int   i32x4;
typedef __attribute__((ext_vector_type(4))) float f32x4;
typedef unsigned short ushort_t;
typedef unsigned int uint_t;

__device__ __forceinline__ char sgn_i8(float v) {
    return v > 0.f ? (char)1 : (v < 0.f ? (char)-1 : (char)0);
}
__device__ __forceinline__ uint_t sgn_b(float v) {
    return (uint_t)(unsigned char)sgn_i8(v);
}

__device__ __forceinline__ void gload16(const void* g, void* l) {
    __builtin_amdgcn_global_load_lds(
        (const __attribute__((address_space(1))) void*)g,
        (__attribute__((address_space(3))) void*)l, 16, 0, 0);
}

// Channel order on the conv1 K axis is IDENTITY: a1p[px][ic], bw1 k = tap*256+ic.

// ---------------------------------------------------------------------------
// Kernel 1 (512 threads): blocks 0..767 weight prep; blocks 768..1279
// sign(x+bias)->a1p + 2x2 avgpool. Phase A = R17 grid-stride, unrolled x2
// with hoisted loads (4 float4 in flight per thread, all threads active).
// ---------------------------------------------------------------------------
__global__ __launch_bounds__(512) void prep_sign(
    const float* __restrict__ w1,
    const float* __restrict__ bn1_g, const float* __restrict__ bn1_b,
    const float* __restrict__ bn1_m, const float* __restrict__ bn1_v,
    const float* __restrict__ w21,
    const float* __restrict__ bn21_g, const float* __restrict__ bn21_b,
    const float* __restrict__ bn21_m, const float* __restrict__ bn21_v,
    const float* __restrict__ w22,
    const float* __restrict__ bn22_g, const float* __restrict__ bn22_b,
    const float* __restrict__ bn22_m, const float* __restrict__ bn22_v,
    const float* __restrict__ x, const float* __restrict__ bias,
    char* __restrict__ bw1, char* __restrict__ bw2,
    float* __restrict__ alpha1, float* __restrict__ beta1,
    float* __restrict__ alpha2, float* __restrict__ beta2,
    char* __restrict__ a1p, float* __restrict__ pool)
{
    __shared__ uint_t lsign[64 * 99];         // [cc][row*7+q], 25.3KB
    float* red = (float*)lsign;               // 512-float reduction aliases it
    const int bid = blockIdx.x;
    const int t = threadIdx.x;

    if (bid < 768) {
        if (bid < 256) {
            const int oc = bid;
            const float* w = w1 + oc * K1;
            float wv[9];
            float s = 0.f;
            if (t < 256) {
#pragma unroll
                for (int k = 0; k < 9; ++k) wv[k] = w[t * 9 + k];
#pragma unroll
                for (int k = 0; k < 9; ++k) s += fabsf(wv[k]);
            }
            red[t] = s; __syncthreads();
            for (int o = 256; o > 0; o >>= 1) {
                if (t < o) red[t] += red[t + o];
                __syncthreads();
            }
            const float scale = red[0] * (1.f / (float)K1);
            if (t == 0) {
                const float inv = bn1_g[oc] * rsqrtf(bn1_v[oc] + EPS_BN);
                alpha1[oc] = scale * inv;
                beta1[oc]  = bn1_b[oc] - bn1_m[oc] * inv;
            }
            if (t < 256) {
#pragma unroll
                for (int tap = 0; tap < 9; ++tap)
                    bw1[oc * K1 + tap * 256 + t] = sgn_i8(wv[tap]);
            }
        } else {
            const bool br2 = (bid >= 512);
            const int oc = (bid - 256) & 255;
            const float* w = (br2 ? w22 : w21) + oc * 256;
            red[t] = (t < 256) ? fabsf(w[t]) : 0.f;
            __syncthreads();
            for (int o = 256; o > 0; o >>= 1) {
                if (t < o) red[t] += red[t + o];
                __syncthreads();
            }
            const float scale = red[0] * (1.f / 256.f);
            const int n = oc + (br2 ? 256 : 0);
            if (t == 0) {
                const float g = br2 ? bn22_g[oc] : bn21_g[oc];
                const float b = br2 ? bn22_b[oc] : bn21_b[oc];
                const float m = br2 ? bn22_m[oc] : bn21_m[oc];
                const float v = br2 ? bn22_v[oc] : bn21_v[oc];
                const float inv = g * rsqrtf(v + EPS_BN);
                alpha2[n] = scale * inv;
                beta2[n]  = b - m * inv;
            }
            if (t < 256) bw2[n * 256 + t] = sgn_i8(w[t]);
        }
        return;
    }

    // ---- sign + pool: block = (b, cq, rh), 512 threads ----
    const int sb = bid - 768;               // b*8 + cq*2 + rh
    const int rh = sb & 1;                  // row half: ih in [14rh, 14rh+14)
    const int cq = (sb >> 1) & 3;           // channels [64cq, 64cq+64)
    const int b = sb >> 3;
    const float* xb = x + ((size_t)(b * 256 + 64 * cq) * 784 + rh * 392);

    // Phase A: unrolled x2, loads hoisted ahead of processing.
    auto procA = [&](int i, const float4& v0, const float4& v1) {
        const int cc = i / 49, o = i - cc * 49;
        const int ihp = o / 7, q = o - ihp * 7;
        const int c = 64 * cq + cc;
        const float bc = bias[c];
        lsign[cc * 99 + (2 * ihp) * 7 + q] =
            sgn_b(v0.x + bc) | (sgn_b(v0.y + bc) << 8) |
            (sgn_b(v0.z + bc) << 16) | (sgn_b(v0.w + bc) << 24);
        lsign[cc * 99 + (2 * ihp + 1) * 7 + q] =
            sgn_b(v1.x + bc) | (sgn_b(v1.y + bc) << 8) |
            (sgn_b(v1.z + bc) << 16) | (sgn_b(v1.w + bc) << 24);
        float2 pr;
        pr.x = 0.25f * (v0.x + v0.y + v1.x + v1.y);
        pr.y = 0.25f * (v0.z + v0.w + v1.z + v1.w);
        *(float2*)(pool + (size_t)(b * 256 + c) * 196
                   + (7 * rh + ihp) * 14 + 2 * q) = pr;
    };
    auto srcA = [&](int i) -> const float* {
        const int cc = i / 49, o = i - cc * 49;
        const int ihp = o / 7, q = o - ihp * 7;
        return xb + cc * 784 + (2 * ihp) * 28 + 4 * q;
    };

    for (int i = t; i < 3136; i += 1024) {
        const int i2 = i + 512;
        const float* sA = srcA(i);
        const float4 a0 = *(const float4*)sA;
        const float4 a1 = *(const float4*)(sA + 28);
        float4 b0, b1;
        const bool has2 = (i2 < 3136);
        if (has2) {
            const float* sB = srcA(i2);
            b0 = *(const float4*)sB;
            b1 = *(const float4*)(sB + 28);
        }
        procA(i, a0, a1);
        if (has2) procA(i2, b0, b1);
    }
    __syncthreads();

    // Phase B: 4ch x 4iw byte transpose; 16 lanes -> 64B contiguous stores.
    {
        const int tw = t & 15;              // word index within c-quarter
        for (int ii = (t >> 4); ii < 392; ii += 32) {   // 14row x 7q x 4j
            const int row = ii / 28, qj = ii - row * 28;
            const int q = qj >> 2, j = qj & 3;
            uint_t d[4];
#pragma unroll
            for (int e = 0; e < 4; ++e)
                d[e] = lsign[(4 * tw + e) * 99 + row * 7 + q];
            const uint_t ov = ((d[0] >> (8 * j)) & 0xffu)
                            | (((d[1] >> (8 * j)) & 0xffu) << 8)
                            | (((d[2] >> (8 * j)) & 0xffu) << 16)
                            | (((d[3] >> (8 * j)) & 0xffu) << 24);
            const int ihp = 14 * rh + row + 1;
            const int iwp = 4 * q + j + 1;
            *(uint_t*)(a1p + (size_t)((b * 30 + ihp) * 30 + iwp) * 256
                       + 64 * cq + 4 * tw) = ov;
        }
        // halo: this block zeroes its 64B channel slice for its row range
        for (int px = (t >> 4); px < 60; px += 32) {
            int ihp, iwp;
            if (px < 15)      { ihp = 15 * rh + px;        iwp = 0;  }
            else if (px < 30) { ihp = 15 * rh + (px - 15); iwp = 29; }
            else              { ihp = 29 * rh;             iwp = px - 30; }
            *(uint_t*)(a1p + (size_t)((b * 30 + ihp) * 30 + iwp) * 256
                       + 64 * cq + 4 * tw) = 0u;
        }
    }
}

// ---------------------------------------------------------------------------
// Kernel 2: conv1 (3x3 s2) i8 GEMM (= R17: prefetch + LDS-transposed epi).
// ---------------------------------------------------------------------------
__global__ __launch_bounds__(512) void conv1_i8(
    const char* __restrict__ a1p,       // [64][30][30][256] i8
    const char* __restrict__ bw1,       // [256][2304] i8 (k = tap*256+ic)
    const float* __restrict__ alpha1, const float* __restrict__ beta1,
    const float* __restrict__ p,
    const float* __restrict__ rsb,
    const float* __restrict__ prg, const float* __restrict__ prb,
    const float* __restrict__ prz,
    float* __restrict__ out2,
    char* __restrict__ a2)              // [m][256] i8
{
    __shared__ char lA[2][64 * 128];    // 16KB (reused: fp32 otile [n][m])
    __shared__ char lB[2][64 * 128];    // 16KB (reused: i8 atile [m][n])

    const int bid = blockIdx.x;
    const int wgid = (bid & 7) * 98 + (bid >> 3);   // 784 = 8*98
    const int mtile = wgid >> 2;
    const int ntile = wgid & 3;

    const int tid = threadIdx.x;
    const int wave = tid >> 6;
    const int lane = tid & 63;
    const int col = lane & 15;
    const int krow = lane >> 4;
    const int wr = wave >> 2;
    const int wc = wave & 3;
    const int l8 = lane >> 3;
    const int s8 = lane & 7;
    const int swz = ((s8 ^ l8) << 4);

    int pbA;
    {
        const int grow = wave * 8 + l8;
        const int m = mtile * 64 + grow;
        const int b = m / 196, r = m % 196;
        const int oh = r / 14, ow = r % 14;
        pbA = ((b * 30 + 2 * oh) * 30 + 2 * ow) * 256 + swz;
    }
    const int pbB = (ntile * 64 + wave * 8 + l8) * K1 + swz;

    int rswz[2];
#pragma unroll
    for (int ks = 0; ks < 2; ++ks)
        rswz[ks] = ((ks * 4 + krow) ^ (col & 7)) << 4;

    // epilogue-operand prefetch (latency hides under the K-loop)
    const int n0e = ntile * 64 + wc * 16 + krow * 4;
    float p_pre[2][4];
#pragma unroll
    for (int im = 0; im < 2; ++im) {
        const int m = mtile * 64 + wr * 32 + im * 16 + col;
        const int b = m / 196, r = m % 196;
#pragma unroll
        for (int j = 0; j < 4; ++j)
            p_pre[im][j] = p[(b * 256 + n0e + j) * 196 + r];
    }

    i32x4 acc[2] = {};

    auto stage = [&](int step, int buf) {
        const int tap = step >> 1;
        const int kc0 = (step & 1) << 7;
        const int kh = tap / 3, kw = tap - kh * 3;
        const int aoff = (kh * 30 + kw) * 256 + kc0;
        gload16(a1p + pbA + aoff, &lA[buf][0] + wave * 1024);
        gload16(bw1 + pbB + step * 128, &lB[buf][0] + wave * 1024);
    };

    stage(0, 0);

    int cur = 0;
    for (int step = 0; step < 18; ++step) {
        if (step + 1 < 18) {
            stage(step + 1, cur ^ 1);
            asm volatile("s_waitcnt vmcnt(2)" ::: "memory");
        } else {
            asm volatile("s_waitcnt vmcnt(0)" ::: "memory");
        }
        __builtin_amdgcn_s_barrier();
        __builtin_amdgcn_sched_barrier(0);

#pragma unroll
        for (int ks = 0; ks < 2; ++ks) {
            i32x4 bf[2], af;
#pragma unroll
            for (int im = 0; im < 2; ++im) {
                const int row = wr * 32 + im * 16 + col;
                bf[im] = *(const i32x4*)(&lA[cur][0] + row * 128 + rswz[ks]);
            }
            {
                const int row = wc * 16 + col;
                af = *(const i32x4*)(&lB[cur][0] + row * 128 + rswz[ks]);
            }
#pragma unroll
            for (int im = 0; im < 2; ++im)
                acc[im] = __builtin_amdgcn_mfma_i32_16x16x64_i8(
                    af, bf[im], acc[im], 0, 0, 0);
        }
        __builtin_amdgcn_sched_barrier(0);
        __builtin_amdgcn_s_barrier();
        cur ^= 1;
    }

    // -------- LDS-transposed epilogue --------
    float* otile = (float*)&lA[0][0];     // [nl][ml] 64x64 f32
    char*  atile = &lB[0][0];             // [ml][nl] 64x64 i8
    __syncthreads();
#pragma unroll
    for (int im = 0; im < 2; ++im) {
        const int ml = wr * 32 + im * 16 + col;
#pragma unroll
        for (int j = 0; j < 4; ++j) {
            const int nl = wc * 16 + krow * 4 + j;
            const int n = ntile * 64 + nl;
            float v = alpha1[n] * (float)acc[im][j] + beta1[n] + p_pre[im][j];
            const float t = v - prg[n];
            const float o = (t > 0.f ? t : prb[n] * t) + prz[n];
            otile[nl * 64 + ml] = o;
            atile[ml * 64 + nl] = sgn_i8(o + rsb[n]);
        }
    }
    __syncthreads();
    {
        const int m = mtile * 64 + lane;
        const int b = m / 196, r = m % 196;
#pragma unroll
        for (int nn = 0; nn < 8; ++nn) {
            const int nl = wave * 8 + nn;
            out2[(b * 256 + ntile * 64 + nl) * 196 + r] = otile[nl * 64 + lane];
        }
    }
    {
        const uint_t* at32 = (const uint_t*)atile;
#pragma unroll
        for (int h = 0; h < 2; ++h) {
            const int idx = h * 512 + tid;
            const int ml = idx >> 4, nq = idx & 15;
            *(uint_t*)(a2 + (size_t)(mtile * 64 + ml) * 256 + ntile * 64 + nq * 4)
                = at32[ml * 16 + nq];
        }
    }
}

// ---------------------------------------------------------------------------
// Kernel 3: both 1x1 convs, single-shot i8 GEMM (= R17).
// ---------------------------------------------------------------------------
__global__ __launch_bounds__(512) void conv1x1_i8(
    const char* __restrict__ a2,
    const char* __restrict__ bw2,
    const float* __restrict__ alpha2, const float* __restrict__ beta2,
    const float* __restrict__ out2,
    const float* __restrict__ prg, const float* __restrict__ prb,
    const float* __restrict__ prz,
    float* __restrict__ out)
{
    __shared__ char lA[2][64 * 128];    // 16KB (reused: fp32 otile [n][m])
    __shared__ char lB[2][64 * 128];

    const int bid = blockIdx.x;
    const int wgid = (bid & 7) * 196 + (bid >> 3);  // 1568 = 8*196
    const int mtile = wgid >> 3;
    const int ntile = wgid & 7;

    const int tid = threadIdx.x;
    const int wave = tid >> 6;
    const int lane = tid & 63;
    const int col = lane & 15;
    const int krow = lane >> 4;
    const int wr = wave >> 2;
    const int wc = wave & 3;
    const int l8 = lane >> 3;
    const int s8 = lane & 7;
    const int swz = ((s8 ^ l8) << 4);

    const int pbA = (mtile * 64 + wave * 8 + l8) * 256 + swz;
    const int pbB = (ntile * 64 + wave * 8 + l8) * 256 + swz;

    const int n0e = ntile * 64 + wc * 16 + krow * 4;
    float o2_pre[2][4];
#pragma unroll
    for (int im = 0; im < 2; ++im) {
        const int m = mtile * 64 + wr * 32 + im * 16 + col;
        const int b = m / 196, r = m % 196;
#pragma unroll
        for (int j = 0; j < 4; ++j)
            o2_pre[im][j] = out2[(b * 256 + ((n0e + j) & 255)) * 196 + r];
    }

#pragma unroll
    for (int h = 0; h < 2; ++h) {
        gload16(a2 + pbA + h * 128, &lA[h][0] + wave * 1024);
        gload16(bw2 + pbB + h * 128, &lB[h][0] + wave * 1024);
    }
    asm volatile("s_waitcnt vmcnt(0)" ::: "memory");
    __builtin_amdgcn_s_barrier();
    __builtin_amdgcn_sched_barrier(0);

    i32x4 acc[2] = {};
#pragma unroll
    for (int ks = 0; ks < 4; ++ks) {
        const int h = ks >> 1, k2 = ks & 1;
        const int ro = ((k2 * 4 + krow) ^ (col & 7)) << 4;
        i32x4 bf[2], af;
#pragma unroll
        for (int im = 0; im < 2; ++im) {
            const int row = wr * 32 + im * 16 + col;
            bf[im] = *(const i32x4*)(&lA[h][0] + row * 128 + ro);
        }
        {
            const int row = wc * 16 + col;
            af = *(const i32x4*)(&lB[h][0] + row * 128 + ro);
        }
#pragma unroll
        for (int im = 0; im < 2; ++im)
            acc[im] = __builtin_amdgcn_mfma_i32_16x16x64_i8(
                af, bf[im], acc[im], 0, 0, 0);
    }

    // -------- LDS-transposed epilogue --------
    float* otile = (float*)&lA[0][0];     // [nl][ml] 64x64 f32
    __syncthreads();
#pragma unroll
    for (int im = 0; im < 2; ++im) {
        const int ml = wr * 32 + im * 16 + col;
#pragma unroll
        for (int j = 0; j < 4; ++j) {
            const int nl = wc * 16 + krow * 4 + j;
            const int n = ntile * 64 + nl;             // [0,512)
            const int oc = n & 255;
            float v = alpha2[n] * (float)acc[im][j] + beta2[n] + o2_pre[im][j];
            const float t = v - prg[oc];
            otile[nl * 64 + ml] = (t > 0.f ? t : prb[oc] * t) + prz[oc];
        }
    }
    __syncthreads();
    {
        const int m = mtile * 64 + lane;
        const int b = m / 196, r = m % 196;
#pragma unroll
        for (int nn = 0; nn < 8; ++nn) {
            const int nl = wave * 8 + nn;
            out[(size_t)(b * 512 + ntile * 64 + nl) * 196 + r]
                = otile[nl * 64 + lane];
        }
    }
}

// ---------------------------------------------------------------------------
extern "C" void kernel_launch(void* const* d_in, const int* in_sizes, int n_in,
                              void* d_out, int out_size, void* d_ws, size_t ws_size,
                              hipStream_t stream)
{
    (void)in_sizes; (void)n_in; (void)out_size; (void)ws_size;

    const float* x         = (const float*)d_in[0];
    const float* rsign_b   = (const float*)d_in[1];
    const float* w1        = (const float*)d_in[2];
    const float* bn1_g     = (const float*)d_in[3];
    const float* bn1_b     = (const float*)d_in[4];
    const float* bn1_m     = (const float*)d_in[5];
    const float* bn1_v     = (const float*)d_in[6];
    const float* w21       = (const float*)d_in[7];
    const float* bn21_g    = (const float*)d_in[8];
    const float* bn21_b    = (const float*)d_in[9];
    const float* bn21_m    = (const float*)d_in[10];
    const float* bn21_v    = (const float*)d_in[11];
    const float* w22       = (const float*)d_in[12];
    const float* bn22_g    = (const float*)d_in[13];
    const float* bn22_b    = (const float*)d_in[14];
    const float* bn22_m    = (const float*)d_in[15];
    const float* bn22_v    = (const float*)d_in[16];
    const float* pr_gamma  = (const float*)d_in[17];
    const float* pr_beta   = (const float*)d_in[18];
    const float* pr_zeta   = (const float*)d_in[19];

    char* ws = (char*)d_ws;
    size_t off = 0;
    char* a1p     = (char*)(ws + off);  off += (size_t)14745600;      // i8
    char* bw1     = (char*)(ws + off);  off += (size_t)589824;        // i8
    char* bw2     = (char*)(ws + off);  off += (size_t)131072;        // i8
    float* pool   = (float*)(ws + off); off += (size_t)3211264 * 4;   // fp32
    float* out2   = (float*)(ws + off); off += (size_t)3211264 * 4;   // fp32
    char* a2      = (char*)(ws + off);  off += (size_t)3211264;       // i8
    float* alpha1 = (float*)(ws + off); off += 1024;
    float* beta1  = (float*)(ws + off); off += 1024;
    float* alpha2 = (float*)(ws + off); off += 2048;
    float* beta2  = (float*)(ws + off); off += 2048;

    prep_sign<<<1280, 512, 0, stream>>>(
        w1, bn1_g, bn1_b, bn1_m, bn1_v,
        w21, bn21_g, bn21_b, bn21_m, bn21_v,
        w22, bn22_g, bn22_b, bn22_m, bn22_v,
        x, rsign_b,
        bw1, bw2, alpha1, beta1, alpha2, beta2, a1p, pool);

    conv1_i8<<<784, 512, 0, stream>>>(
        a1p, bw1, alpha1, beta1, pool, rsign_b,
        pr_gamma, pr_beta, pr_zeta, out2, a2);

    conv1x1_i8<<<1568, 512, 0, stream>>>(
        a2, bw2, alpha2, beta2, out2,
        pr_gamma, pr_beta, pr_zeta, (float*)d_out);
}

// Round 20
// 53.183 us; speedup vs baseline: 1.1304x; 1.0605x over previous
//
#include <hip/hip_runtime.h>
#include <stdint.h>

#define EPS_BN 1e-5f

#define C 256
#define H 28
#define W 28
#define R196 196
#define M_TOT 12544
#define K1 2304

typedef __attribute__((ext_vector_type(4))) int   i32x4;
typedef __attribute__((ext_vector_type(4))) float f32x4;
typedef unsigned short ushort_t;
typedef unsigned int uint_t;

__device__ __forceinline__ char sgn_i8(float v) {
    return v > 0.f ? (char)1 : (v < 0.f ? (char)-1 : (char)0);
}
__device__ __forceinline__ uint_t sgn_b(float v) {
    return (uint_t)(unsigned char)sgn_i8(v);
}

__device__ __forceinline__ void gload16(const void* g, void* l) {
    __builtin_amdgcn_global_load_lds(
        (const __attribute__((address_space(1))) void*)g,
        (__attribute__((address_space(3))) void*)l, 16, 0, 0);
}

// Channel order on the conv1 K axis is IDENTITY: a1p[px][ic], bw1 k = tap*256+ic.

// ---------------------------------------------------------------------------
// Kernel 1 (512 threads): blocks 0..767 weight prep; blocks 768..1279
// sign(x+bias)->a1p + 2x2 avgpool. (= R17, session best)
// ---------------------------------------------------------------------------
__global__ __launch_bounds__(512) void prep_sign(
    const float* __restrict__ w1,
    const float* __restrict__ bn1_g, const float* __restrict__ bn1_b,
    const float* __restrict__ bn1_m, const float* __restrict__ bn1_v,
    const float* __restrict__ w21,
    const float* __restrict__ bn21_g, const float* __restrict__ bn21_b,
    const float* __restrict__ bn21_m, const float* __restrict__ bn21_v,
    const float* __restrict__ w22,
    const float* __restrict__ bn22_g, const float* __restrict__ bn22_b,
    const float* __restrict__ bn22_m, const float* __restrict__ bn22_v,
    const float* __restrict__ x, const float* __restrict__ bias,
    char* __restrict__ bw1, char* __restrict__ bw2,
    float* __restrict__ alpha1, float* __restrict__ beta1,
    float* __restrict__ alpha2, float* __restrict__ beta2,
    char* __restrict__ a1p, float* __restrict__ pool)
{
    __shared__ uint_t lsign[64 * 99];         // [cc][row*7+q], 25.3KB
    float* red = (float*)lsign;               // 512-float reduction aliases it
    const int bid = blockIdx.x;
    const int t = threadIdx.x;

    if (bid < 768) {
        if (bid < 256) {
            const int oc = bid;
            const float* w = w1 + oc * K1;
            float wv[9];
            float s = 0.f;
            if (t < 256) {
#pragma unroll
                for (int k = 0; k < 9; ++k) wv[k] = w[t * 9 + k];
#pragma unroll
                for (int k = 0; k < 9; ++k) s += fabsf(wv[k]);
            }
            red[t] = s; __syncthreads();
            for (int o = 256; o > 0; o >>= 1) {
                if (t < o) red[t] += red[t + o];
                __syncthreads();
            }
            const float scale = red[0] * (1.f / (float)K1);
            if (t == 0) {
                const float inv = bn1_g[oc] * rsqrtf(bn1_v[oc] + EPS_BN);
                alpha1[oc] = scale * inv;
                beta1[oc]  = bn1_b[oc] - bn1_m[oc] * inv;
            }
            if (t < 256) {
#pragma unroll
                for (int tap = 0; tap < 9; ++tap)
                    bw1[oc * K1 + tap * 256 + t] = sgn_i8(wv[tap]);
            }
        } else {
            const bool br2 = (bid >= 512);
            const int oc = (bid - 256) & 255;
            const float* w = (br2 ? w22 : w21) + oc * 256;
            red[t] = (t < 256) ? fabsf(w[t]) : 0.f;
            __syncthreads();
            for (int o = 256; o > 0; o >>= 1) {
                if (t < o) red[t] += red[t + o];
                __syncthreads();
            }
            const float scale = red[0] * (1.f / 256.f);
            const int n = oc + (br2 ? 256 : 0);
            if (t == 0) {
                const float g = br2 ? bn22_g[oc] : bn21_g[oc];
                const float b = br2 ? bn22_b[oc] : bn21_b[oc];
                const float m = br2 ? bn22_m[oc] : bn21_m[oc];
                const float v = br2 ? bn22_v[oc] : bn21_v[oc];
                const float inv = g * rsqrtf(v + EPS_BN);
                alpha2[n] = scale * inv;
                beta2[n]  = b - m * inv;
            }
            if (t < 256) bw2[n * 256 + t] = sgn_i8(w[t]);
        }
        return;
    }

    // ---- sign + pool: block = (b, cq, rh), 512 threads ----
    const int sb = bid - 768;               // b*8 + cq*2 + rh
    const int rh = sb & 1;                  // row half: ih in [14rh, 14rh+14)
    const int cq = (sb >> 1) & 3;           // channels [64cq, 64cq+64)
    const int b = sb >> 3;
    const float* xb = x + ((size_t)(b * 256 + 64 * cq) * 784 + rh * 392);

    // Phase A: contiguous reads; signs -> LDS; pool computed in-register.
    for (int i = t; i < 3136; i += 512) {   // 64cc x 7ihp x 7q
        const int cc = i / 49, o = i - cc * 49;
        const int ihp = o / 7, q = o - ihp * 7;     // local row-pair, iw-quad
        const int c = 64 * cq + cc;
        const float bc = bias[c];
        const float* src = xb + cc * 784 + (2 * ihp) * 28 + 4 * q;
        const float4 v0 = *(const float4*)src;
        const float4 v1 = *(const float4*)(src + 28);
        lsign[cc * 99 + (2 * ihp) * 7 + q] =
            sgn_b(v0.x + bc) | (sgn_b(v0.y + bc) << 8) |
            (sgn_b(v0.z + bc) << 16) | (sgn_b(v0.w + bc) << 24);
        lsign[cc * 99 + (2 * ihp + 1) * 7 + q] =
            sgn_b(v1.x + bc) | (sgn_b(v1.y + bc) << 8) |
            (sgn_b(v1.z + bc) << 16) | (sgn_b(v1.w + bc) << 24);
        float2 pr;
        pr.x = 0.25f * (v0.x + v0.y + v1.x + v1.y);
        pr.y = 0.25f * (v0.z + v0.w + v1.z + v1.w);
        *(float2*)(pool + (size_t)(b * 256 + c) * 196
                   + (7 * rh + ihp) * 14 + 2 * q) = pr;
    }
    __syncthreads();

    // Phase B: 4ch x 4iw byte transpose; 16 lanes -> 64B contiguous stores.
    {
        const int tw = t & 15;              // word index within c-quarter
        for (int ii = (t >> 4); ii < 392; ii += 32) {   // 14row x 7q x 4j
            const int row = ii / 28, qj = ii - row * 28;
            const int q = qj >> 2, j = qj & 3;
            uint_t d[4];
#pragma unroll
            for (int e = 0; e < 4; ++e)
                d[e] = lsign[(4 * tw + e) * 99 + row * 7 + q];
            const uint_t ov = ((d[0] >> (8 * j)) & 0xffu)
                            | (((d[1] >> (8 * j)) & 0xffu) << 8)
                            | (((d[2] >> (8 * j)) & 0xffu) << 16)
                            | (((d[3] >> (8 * j)) & 0xffu) << 24);
            const int ihp = 14 * rh + row + 1;
            const int iwp = 4 * q + j + 1;
            *(uint_t*)(a1p + (size_t)((b * 30 + ihp) * 30 + iwp) * 256
                       + 64 * cq + 4 * tw) = ov;
        }
        // halo: this block zeroes its 64B channel slice for its row range
        for (int px = (t >> 4); px < 60; px += 32) {
            int ihp, iwp;
            if (px < 15)      { ihp = 15 * rh + px;        iwp = 0;  }
            else if (px < 30) { ihp = 15 * rh + (px - 15); iwp = 29; }
            else              { ihp = 29 * rh;             iwp = px - 30; }
            *(uint_t*)(a1p + (size_t)((b * 30 + ihp) * 30 + iwp) * 256
                       + 64 * cq + 4 * tw) = 0u;
        }
    }
}

// ---------------------------------------------------------------------------
// Kernel 2: conv1 (3x3 s2) i8 GEMM (prefetch + LDS-transposed epilogue).
// ---------------------------------------------------------------------------
__global__ __launch_bounds__(512) void conv1_i8(
    const char* __restrict__ a1p,       // [64][30][30][256] i8
    const char* __restrict__ bw1,       // [256][2304] i8 (k = tap*256+ic)
    const float* __restrict__ alpha1, const float* __restrict__ beta1,
    const float* __restrict__ p,
    const float* __restrict__ rsb,
    const float* __restrict__ prg, const float* __restrict__ prb,
    const float* __restrict__ prz,
    float* __restrict__ out2,
    char* __restrict__ a2)              // [m][256] i8
{
    __shared__ char lA[2][64 * 128];    // 16KB (reused: fp32 otile [n][m])
    __shared__ char lB[2][64 * 128];    // 16KB (reused: i8 atile [m][n])

    const int bid = blockIdx.x;
    const int wgid = (bid & 7) * 98 + (bid >> 3);   // 784 = 8*98
    const int mtile = wgid >> 2;
    const int ntile = wgid & 3;

    const int tid = threadIdx.x;
    const int wave = tid >> 6;
    const int lane = tid & 63;
    const int col = lane & 15;
    const int krow = lane >> 4;
    const int wr = wave >> 2;
    const int wc = wave & 3;
    const int l8 = lane >> 3;
    const int s8 = lane & 7;
    const int swz = ((s8 ^ l8) << 4);

    int pbA;
    {
        const int grow = wave * 8 + l8;
        const int m = mtile * 64 + grow;
        const int b = m / 196, r = m % 196;
        const int oh = r / 14, ow = r % 14;
        pbA = ((b * 30 + 2 * oh) * 30 + 2 * ow) * 256 + swz;
    }
    const int pbB = (ntile * 64 + wave * 8 + l8) * K1 + swz;

    int rswz[2];
#pragma unroll
    for (int ks = 0; ks < 2; ++ks)
        rswz[ks] = ((ks * 4 + krow) ^ (col & 7)) << 4;

    // epilogue-operand prefetch (latency hides under the K-loop)
    const int n0e = ntile * 64 + wc * 16 + krow * 4;
    float p_pre[2][4];
#pragma unroll
    for (int im = 0; im < 2; ++im) {
        const int m = mtile * 64 + wr * 32 + im * 16 + col;
        const int b = m / 196, r = m % 196;
#pragma unroll
        for (int j = 0; j < 4; ++j)
            p_pre[im][j] = p[(b * 256 + n0e + j) * 196 + r];
    }

    i32x4 acc[2] = {};

    auto stage = [&](int step, int buf) {
        const int tap = step >> 1;
        const int kc0 = (step & 1) << 7;
        const int kh = tap / 3, kw = tap - kh * 3;
        const int aoff = (kh * 30 + kw) * 256 + kc0;
        gload16(a1p + pbA + aoff, &lA[buf][0] + wave * 1024);
        gload16(bw1 + pbB + step * 128, &lB[buf][0] + wave * 1024);
    };

    stage(0, 0);

    int cur = 0;
    for (int step = 0; step < 18; ++step) {
        if (step + 1 < 18) {
            stage(step + 1, cur ^ 1);
            asm volatile("s_waitcnt vmcnt(2)" ::: "memory");
        } else {
            asm volatile("s_waitcnt vmcnt(0)" ::: "memory");
        }
        __builtin_amdgcn_s_barrier();
        __builtin_amdgcn_sched_barrier(0);

#pragma unroll
        for (int ks = 0; ks < 2; ++ks) {
            i32x4 bf[2], af;
#pragma unroll
            for (int im = 0; im < 2; ++im) {
                const int row = wr * 32 + im * 16 + col;
                bf[im] = *(const i32x4*)(&lA[cur][0] + row * 128 + rswz[ks]);
            }
            {
                const int row = wc * 16 + col;
                af = *(const i32x4*)(&lB[cur][0] + row * 128 + rswz[ks]);
            }
#pragma unroll
            for (int im = 0; im < 2; ++im)
                acc[im] = __builtin_amdgcn_mfma_i32_16x16x64_i8(
                    af, bf[im], acc[im], 0, 0, 0);
        }
        __builtin_amdgcn_sched_barrier(0);
        __builtin_amdgcn_s_barrier();
        cur ^= 1;
    }

    // -------- LDS-transposed epilogue --------
    float* otile = (float*)&lA[0][0];     // [nl][ml] 64x64 f32
    char*  atile = &lB[0][0];             // [ml][nl] 64x64 i8
    __syncthreads();
#pragma unroll
    for (int im = 0; im < 2; ++im) {
        const int ml = wr * 32 + im * 16 + col;
#pragma unroll
        for (int j = 0; j < 4; ++j) {
            const int nl = wc * 16 + krow * 4 + j;
            const int n = ntile * 64 + nl;
            float v = alpha1[n] * (float)acc[im][j] + beta1[n] + p_pre[im][j];
            const float t = v - prg[n];
            const float o = (t > 0.f ? t : prb[n] * t) + prz[n];
            otile[nl * 64 + ml] = o;
            atile[ml * 64 + nl] = sgn_i8(o + rsb[n]);
        }
    }
    __syncthreads();
    {
        const int m = mtile * 64 + lane;
        const int b = m / 196, r = m % 196;
#pragma unroll
        for (int nn = 0; nn < 8; ++nn) {
            const int nl = wave * 8 + nn;
            out2[(b * 256 + ntile * 64 + nl) * 196 + r] = otile[nl * 64 + lane];
        }
    }
    {
        const uint_t* at32 = (const uint_t*)atile;
#pragma unroll
        for (int h = 0; h < 2; ++h) {
            const int idx = h * 512 + tid;
            const int ml = idx >> 4, nq = idx & 15;
            *(uint_t*)(a2 + (size_t)(mtile * 64 + ml) * 256 + ntile * 64 + nq * 4)
                = at32[ml * 16 + nq];
        }
    }
}

// ---------------------------------------------------------------------------
// Kernel 3: both 1x1 convs, single-shot i8 GEMM.
// ---------------------------------------------------------------------------
__global__ __launch_bounds__(512) void conv1x1_i8(
    const char* __restrict__ a2,
    const char* __restrict__ bw2,
    const float* __restrict__ alpha2, const float* __restrict__ beta2,
    const float* __restrict__ out2,
    const float* __restrict__ prg, const float* __restrict__ prb,
    const float* __restrict__ prz,
    float* __restrict__ out)
{
    __shared__ char lA[2][64 * 128];    // 16KB (reused: fp32 otile [n][m])
    __shared__ char lB[2][64 * 128];

    const int bid = blockIdx.x;
    const int wgid = (bid & 7) * 196 + (bid >> 3);  // 1568 = 8*196
    const int mtile = wgid >> 3;
    const int ntile = wgid & 7;

    const int tid = threadIdx.x;
    const int wave = tid >> 6;
    const int lane = tid & 63;
    const int col = lane & 15;
    const int krow = lane >> 4;
    const int wr = wave >> 2;
    const int wc = wave & 3;
    const int l8 = lane >> 3;
    const int s8 = lane & 7;
    const int swz = ((s8 ^ l8) << 4);

    const int pbA = (mtile * 64 + wave * 8 + l8) * 256 + swz;
    const int pbB = (ntile * 64 + wave * 8 + l8) * 256 + swz;

    const int n0e = ntile * 64 + wc * 16 + krow * 4;
    float o2_pre[2][4];
#pragma unroll
    for (int im = 0; im < 2; ++im) {
        const int m = mtile * 64 + wr * 32 + im * 16 + col;
        const int b = m / 196, r = m % 196;
#pragma unroll
        for (int j = 0; j < 4; ++j)
            o2_pre[im][j] = out2[(b * 256 + ((n0e + j) & 255)) * 196 + r];
    }

#pragma unroll
    for (int h = 0; h < 2; ++h) {
        gload16(a2 + pbA + h * 128, &lA[h][0] + wave * 1024);
        gload16(bw2 + pbB + h * 128, &lB[h][0] + wave * 1024);
    }
    asm volatile("s_waitcnt vmcnt(0)" ::: "memory");
    __builtin_amdgcn_s_barrier();
    __builtin_amdgcn_sched_barrier(0);

    i32x4 acc[2] = {};
#pragma unroll
    for (int ks = 0; ks < 4; ++ks) {
        const int h = ks >> 1, k2 = ks & 1;
        const int ro = ((k2 * 4 + krow) ^ (col & 7)) << 4;
        i32x4 bf[2], af;
#pragma unroll
        for (int im = 0; im < 2; ++im) {
            const int row = wr * 32 + im * 16 + col;
            bf[im] = *(const i32x4*)(&lA[h][0] + row * 128 + ro);
        }
        {
            const int row = wc * 16 + col;
            af = *(const i32x4*)(&lB[h][0] + row * 128 + ro);
        }
#pragma unroll
        for (int im = 0; im < 2; ++im)
            acc[im] = __builtin_amdgcn_mfma_i32_16x16x64_i8(
                af, bf[im], acc[im], 0, 0, 0);
    }

    // -------- LDS-transposed epilogue --------
    float* otile = (float*)&lA[0][0];     // [nl][ml] 64x64 f32
    __syncthreads();
#pragma unroll
    for (int im = 0; im < 2; ++im) {
        const int ml = wr * 32 + im * 16 + col;
#pragma unroll
        for (int j = 0; j < 4; ++j) {
            const int nl = wc * 16 + krow * 4 + j;
            const int n = ntile * 64 + nl;             // [0,512)
            const int oc = n & 255;
            float v = alpha2[n] * (float)acc[im][j] + beta2[n] + o2_pre[im][j];
            const float t = v - prg[oc];
            otile[nl * 64 + ml] = (t > 0.f ? t : prb[oc] * t) + prz[oc];
        }
    }
    __syncthreads();
    {
        const int m = mtile * 64 + lane;
        const int b = m / 196, r = m % 196;
#pragma unroll
        for (int nn = 0; nn < 8; ++nn) {
            const int nl = wave * 8 + nn;
            out[(size_t)(b * 512 + ntile * 64 + nl) * 196 + r]
                = otile[nl * 64 + lane];
        }
    }
}

// ---------------------------------------------------------------------------
extern "C" void kernel_launch(void* const* d_in, const int* in_sizes, int n_in,
                              void* d_out, int out_size, void* d_ws, size_t ws_size,
                              hipStream_t stream)
{
    (void)in_sizes; (void)n_in; (void)out_size; (void)ws_size;

    const float* x         = (const float*)d_in[0];
    const float* rsign_b   = (const float*)d_in[1];
    const float* w1        = (const float*)d_in[2];
    const float* bn1_g     = (const float*)d_in[3];
    const float* bn1_b     = (const float*)d_in[4];
    const float* bn1_m     = (const float*)d_in[5];
    const float* bn1_v     = (const float*)d_in[6];
    const float* w21       = (const float*)d_in[7];
    const float* bn21_g    = (const float*)d_in[8];
    const float* bn21_b    = (const float*)d_in[9];
    const float* bn21_m    = (const float*)d_in[10];
    const float* bn21_v    = (const float*)d_in[11];
    const float* w22       = (const float*)d_in[12];
    const float* bn22_g    = (const float*)d_in[13];
    const float* bn22_b    = (const float*)d_in[14];
    const float* bn22_m    = (const float*)d_in[15];
    const float* bn22_v    = (const float*)d_in[16];
    const float* pr_gamma  = (const float*)d_in[17];
    const float* pr_beta   = (const float*)d_in[18];
    const float* pr_zeta   = (const float*)d_in[19];

    char* ws = (char*)d_ws;
    size_t off = 0;
    char* a1p     = (char*)(ws + off);  off += (size_t)14745600;      // i8
    char* bw1     = (char*)(ws + off);  off += (size_t)589824;        // i8
    char* bw2     = (char*)(ws + off);  off += (size_t)131072;        // i8
    float* pool   = (float*)(ws + off); off += (size_t)3211264 * 4;   // fp32
    float* out2   = (float*)(ws + off); off += (size_t)3211264 * 4;   // fp32
    char* a2      = (char*)(ws + off);  off += (size_t)3211264;       // i8
    float* alpha1 = (float*)(ws + off); off += 1024;
    float* beta1  = (float*)(ws + off); off += 1024;
    float* alpha2 = (float*)(ws + off); off += 2048;
    float* beta2  = (float*)(ws + off); off += 2048;

    prep_sign<<<1280, 512, 0, stream>>>(
        w1, bn1_g, bn1_b, bn1_m, bn1_v,
        w21, bn21_g, bn21_b, bn21_m, bn21_v,
        w22, bn22_g, bn22_b, bn22_m, bn22_v,
        x, rsign_b,
        bw1, bw2, alpha1, beta1, alpha2, beta2, a1p, pool);

    conv1_i8<<<784, 512, 0, stream>>>(
        a1p, bw1, alpha1, beta1, pool, rsign_b,
        pr_gamma, pr_beta, pr_zeta, out2, a2);

    conv1x1_i8<<<1568, 512, 0, stream>>>(
        a2, bw2, alpha2, beta2, out2,
        pr_gamma, pr_beta, pr_zeta, (float*)d_out);
}